// Round 8
// baseline (428.929 us; speedup 1.0000x reference)
//
#include <hip/hip_runtime.h>
#include <math.h>

// ---------------------------------------------------------------------------
// SelfAttention R10: base = R7 attn shape (best) + exp2-fold (safe).
//  * k_attn: Ps stride 80 -> 72 (P-store 4-way->2-way conflict, P-read
//    2-way->free); next-tile loads issued BEFORE the visibility barrier.
//  * k_qkv / k_proj / k_prep unchanged from R9.
// ---------------------------------------------------------------------------

typedef __bf16 bf16_t;
typedef __bf16 bf16x8 __attribute__((ext_vector_type(8)));
typedef __bf16 bf16x4v __attribute__((ext_vector_type(4)));
typedef float  f32x4  __attribute__((ext_vector_type(4)));

#define B_  2
#define T_  2048
#define C_  2048
#define SLICE_ ((size_t)B_ * T_ * C_)  // 8388608

__device__ __forceinline__ void glds16(const void* g, void* l) {
  __builtin_amdgcn_global_load_lds(
      (__attribute__((address_space(1))) void*)(void*)(const_cast<void*>(g)),
      (__attribute__((address_space(3))) void*)(l), 16, 0, 0);
}

// ------------------------- fused f32->bf16 packs + rope table --------------
__global__ __launch_bounds__(256) void k_prep(
    const float4* __restrict__ x, const float4* __restrict__ wqkv,
    const float4* __restrict__ wproj, bf16x4v* __restrict__ xb,
    bf16x4v* __restrict__ wqkvb, bf16x4v* __restrict__ wprojb,
    float2* __restrict__ tab) {
  int i = blockIdx.x * 256 + threadIdx.x;
  if (i < 2097152) {
    float4 v = x[i];
    bf16x4v o;
    o[0] = (bf16_t)v.x; o[1] = (bf16_t)v.y; o[2] = (bf16_t)v.z; o[3] = (bf16_t)v.w;
    xb[i] = o;
  } else if (i < 5242880) {
    int j = i - 2097152;
    float4 v = wqkv[j];
    bf16x4v o;
    o[0] = (bf16_t)v.x; o[1] = (bf16_t)v.y; o[2] = (bf16_t)v.z; o[3] = (bf16_t)v.w;
    wqkvb[j] = o;
  } else if (i < 6291456) {
    int j = i - 5242880;
    float4 v = wproj[j];
    bf16x4v o;
    o[0] = (bf16_t)v.x; o[1] = (bf16_t)v.y; o[2] = (bf16_t)v.z; o[3] = (bf16_t)v.w;
    wprojb[j] = o;
  } else {
    int j = i - 6291456;  // 0..131071
    int t = j >> 6, jj = j & 63;
    float thf = (float)pow(10000.0, -(double)(2 * jj) / 128.0);
    float angf = (float)t * thf;
    double a = (double)angf;
    tab[j] = make_float2((float)cos(a), (float)sin(a));
  }
}

// ------------------------- QKV GEMM + RoPE epilogue ------------------------
// C[m,n] = sum_k X[m,k] W[n,k]; M=4096, N=6144, K=2048. 128x128 tile, BK=64.
// LDS tiles xor-swizzled: LDS[row, c'] = global[row, c' ^ (row&7)] (16B chunks)
__global__ __launch_bounds__(256, 2) void k_qkv(
    const bf16_t* __restrict__ X, const bf16_t* __restrict__ W,
    const float2* __restrict__ tab,
    bf16_t* __restrict__ qb, bf16_t* __restrict__ kb, bf16_t* __restrict__ vtb,
    float* __restrict__ kout, float* __restrict__ vout) {
  const int K = 2048;
  __shared__ alignas(16) bf16_t smem[17408];  // As|Bs (16384) U epilogue 128x136
  bf16_t* As = smem;
  bf16_t* Bs = smem + 8192;
  const int tid = threadIdx.x;
  const int lane = tid & 63, wv = tid >> 6;
  const int wm = wv >> 1, wn = wv & 1;
  const int q4 = lane >> 4, l16 = lane & 15;
  const int m0 = blockIdx.x * 128, n0 = blockIdx.y * 128;

  const bf16_t* Ab = X + (size_t)m0 * K;
  const bf16_t* Wb = W + (size_t)n0 * K;

  f32x4 zero4 = {0.f, 0.f, 0.f, 0.f};
  f32x4 acc[4][4];
#pragma unroll
  for (int i = 0; i < 4; ++i)
#pragma unroll
    for (int j = 0; j < 4; ++j) acc[i][j] = zero4;

  for (int k0 = 0; k0 < K; k0 += 64) {
    __syncthreads();
#pragma unroll
    for (int i = 0; i < 4; ++i) {  // 128 rows x 8 chunks
      int ci = i * 256 + tid;
      glds16(Ab + (size_t)(ci >> 3) * K + k0 + (((ci & 7) ^ ((ci >> 3) & 7)) << 3),
             &As[(i * 256 + wv * 64) * 8]);
    }
#pragma unroll
    for (int i = 0; i < 4; ++i) {
      int ci = i * 256 + tid;
      glds16(Wb + (size_t)(ci >> 3) * K + k0 + (((ci & 7) ^ ((ci >> 3) & 7)) << 3),
             &Bs[(i * 256 + wv * 64) * 8]);
    }
    __syncthreads();
#pragma unroll
    for (int kk = 0; kk < 2; ++kk) {
      bf16x8 afrag[4], bfrag[4];
#pragma unroll
      for (int mf = 0; mf < 4; ++mf)
        afrag[mf] = *(const bf16x8*)&As[(wm * 64 + mf * 16 + l16) * 64 +
                                        ((((kk << 2) | q4) ^ (l16 & 7)) << 3)];
#pragma unroll
      for (int nf = 0; nf < 4; ++nf)
        bfrag[nf] = *(const bf16x8*)&Bs[(wn * 64 + nf * 16 + l16) * 64 +
                                        ((((kk << 2) | q4) ^ (l16 & 7)) << 3)];
#pragma unroll
      for (int mf = 0; mf < 4; ++mf)
#pragma unroll
        for (int nf = 0; nf < 4; ++nf)
          acc[mf][nf] = __builtin_amdgcn_mfma_f32_16x16x32_bf16(
              afrag[mf], bfrag[nf], acc[mf][nf], 0, 0, 0);
    }
  }

  __syncthreads();  // smem reuse for epilogue staging
  const int sec = n0 >> 11;  // 0=q, 1=k, 2=v (block-uniform)
  const int t0 = m0 & 2047, bb = m0 >> 11, h = (n0 & 2047) >> 7;

  if (sec < 2) {
#pragma unroll
    for (int mf = 0; mf < 4; ++mf)
#pragma unroll
      for (int nf = 0; nf < 4; ++nf)
#pragma unroll
        for (int r = 0; r < 4; ++r) {
          int ml = wm * 64 + mf * 16 + q4 * 4 + r;
          int d = wn * 64 + nf * 16 + l16;
          float val = acc[mf][nf][r];
          float partner = __shfl_xor(val, 1);
          float2 cs = tab[(t0 + ml) * 64 + (d >> 1)];
          float rv = (d & 1) ? (val * cs.x + partner * cs.y)
                             : (val * cs.x - partner * cs.y);
          // fold 1/sqrt(hd) * log2(e) into q (attn uses exp2)
          if (sec == 0) rv *= 0.08838834764831845f * 1.4426950408889634f;
          else kout[(size_t)(m0 + ml) * 2048 + h * 128 + d] = val;
          smem[ml * 136 + d] = (bf16_t)rv;
        }
    __syncthreads();
    bf16_t* dst = (sec == 0 ? qb : kb);
    size_t gbase = ((size_t)(bb * 16 + h) * 2048 + t0) * 128;
#pragma unroll
    for (int i = 0; i < 8; ++i) {
      int ci = i * 256 + tid, ml = ci >> 4, cc = (ci & 15) * 8;
      *(bf16x8*)(dst + gbase + (size_t)ml * 128 + cc) =
          *(const bf16x8*)&smem[ml * 136 + cc];
    }
  } else {
#pragma unroll
    for (int mf = 0; mf < 4; ++mf)
#pragma unroll
      for (int nf = 0; nf < 4; ++nf)
#pragma unroll
        for (int r = 0; r < 4; ++r) {
          int ml = wm * 64 + mf * 16 + q4 * 4 + r;
          int d = wn * 64 + nf * 16 + l16;
          float val = acc[mf][nf][r];
          vout[((size_t)(bb * 16 + h) * 2048 + t0 + ml) * 128 + d] = val;
          smem[d * 136 + ml] = (bf16_t)val;  // transpose in LDS
        }
    __syncthreads();
#pragma unroll
    for (int i = 0; i < 8; ++i) {
      int ci = i * 256 + tid, dr = ci >> 4, cc = (ci & 15) * 8;
      *(bf16x8*)(vtb + ((size_t)((bb * 16 + h) * 128 + dr)) * 2048 + t0 + cc) =
          *(const bf16x8*)&smem[dr * 136 + cc];
    }
  }
}

// ------------------------- flash attention ---------------------------------
// block = (b,h) x 128 queries, 4 waves x 32 queries. KT=64. Q in registers.
// No-max softmax in exp2 domain (q pre-scaled by log2e/sqrt(hd)).
// T14 async-STAGE; Ps stride 72 (store 2-way, read conflict-free); next-tile
// loads issued before the visibility barrier.
__global__ __launch_bounds__(256, 2) void k_attn(
    const bf16_t* __restrict__ qb, const bf16_t* __restrict__ kb,
    const bf16_t* __restrict__ vtb, bf16_t* __restrict__ ob) {
  __shared__ alignas(16) bf16_t Ps[128 * 72];   // P tile, stride 72
  __shared__ alignas(16) bf16_t Ks[64 * 128];   // swizzled
  __shared__ alignas(16) bf16_t Vts[128 * 64];  // swizzled, [d][key]

  const int tid = threadIdx.x;
  const int lane = tid & 63, wv = tid >> 6;
  const int q4 = lane >> 4, l16 = lane & 15;
  const int bh = blockIdx.x >> 4;
  const int q0 = (blockIdx.x & 15) * 128;

  const bf16_t* Qg = qb + (size_t)bh * T_ * 128 + (size_t)q0 * 128;
  const bf16_t* Kg = kb + (size_t)bh * T_ * 128;
  const bf16_t* Vg = vtb + (size_t)bh * 128 * T_;

  // Q frags straight from global (one-time, pre-scaled by log2e/sqrt(hd))
  bf16x8 qa[2][4];
#pragma unroll
  for (int mf = 0; mf < 2; ++mf)
#pragma unroll
    for (int kf = 0; kf < 4; ++kf)
      qa[mf][kf] = *(const bf16x8*)(Qg + (size_t)(wv * 32 + mf * 16 + l16) * 128 +
                                    kf * 32 + q4 * 8);

  f32x4 zero4 = {0.f, 0.f, 0.f, 0.f};
  float lrow[2][4];
  f32x4 oacc[2][8];
#pragma unroll
  for (int mf = 0; mf < 2; ++mf) {
#pragma unroll
    for (int r = 0; r < 4; ++r) lrow[mf][r] = 0.f;
#pragma unroll
    for (int nf = 0; nf < 8; ++nf) oacc[mf][nf] = zero4;
  }

  // ---- issue staging loads for tile 0 (K: 64x128, V: 128x64, swizzled) ----
  bf16x8 kst[4], vst[4];
#pragma unroll
  for (int i = 0; i < 4; ++i) {
    int ci = i * 256 + tid;
    kst[i] = *(const bf16x8*)(Kg + (size_t)(ci >> 4) * 128 +
                              (((ci & 15) ^ ((ci >> 4) & 7)) << 3));
    vst[i] = *(const bf16x8*)(Vg + (size_t)(ci >> 3) * T_ +
                              (((ci & 7) ^ ((ci >> 3) & 7)) << 3));
  }

  for (int key0 = 0; key0 < T_; key0 += 64) {
    __syncthreads();  // previous compute done reading Ks/Vts
#pragma unroll
    for (int i = 0; i < 4; ++i) {  // write staged regs (waits vmcnt via dep)
      int ci = i * 256 + tid;
      *(bf16x8*)&Ks[ci * 8] = kst[i];
      *(bf16x8*)&Vts[ci * 8] = vst[i];
    }
    if (key0 + 64 < T_) {  // issue NEXT tile's loads before the barrier
      const bf16_t* Kg2 = Kg + (size_t)(key0 + 64) * 128;
      const bf16_t* Vg2 = Vg + key0 + 64;
#pragma unroll
      for (int i = 0; i < 4; ++i) {
        int ci = i * 256 + tid;
        kst[i] = *(const bf16x8*)(Kg2 + (size_t)(ci >> 4) * 128 +
                                  (((ci & 15) ^ ((ci >> 4) & 7)) << 3));
        vst[i] = *(const bf16x8*)(Vg2 + (size_t)(ci >> 3) * T_ +
                                  (((ci & 7) ^ ((ci >> 3) & 7)) << 3));
      }
    }
    __syncthreads();  // writes visible

    // S = Q K^T (pre-scaled, log2 domain)
    f32x4 sacc[2][4];
#pragma unroll
    for (int mf = 0; mf < 2; ++mf)
#pragma unroll
      for (int nf = 0; nf < 4; ++nf) sacc[mf][nf] = zero4;
#pragma unroll
    for (int kf = 0; kf < 4; ++kf) {
      bf16x8 bfrag[4];
#pragma unroll
      for (int nf = 0; nf < 4; ++nf)
        bfrag[nf] = *(const bf16x8*)&Ks[(nf * 16 + l16) * 128 +
                                        ((((kf << 2) | q4) ^ (l16 & 7)) << 3)];
#pragma unroll
      for (int mf = 0; mf < 2; ++mf)
#pragma unroll
        for (int nf = 0; nf < 4; ++nf)
          sacc[mf][nf] = __builtin_amdgcn_mfma_f32_16x16x32_bf16(
              qa[mf][kf], bfrag[nf], sacc[mf][nf], 0, 0, 0);
    }

    // 2^s + P to LDS; per-lane partial row sums (reduced after key loop)
#pragma unroll
    for (int mf = 0; mf < 2; ++mf) {
#pragma unroll
      for (int r = 0; r < 4; ++r) {
        float p0 = exp2f(sacc[mf][0][r]);
        float p1 = exp2f(sacc[mf][1][r]);
        float p2 = exp2f(sacc[mf][2][r]);
        float p3 = exp2f(sacc[mf][3][r]);
        int prow = wv * 32 + mf * 16 + q4 * 4 + r;
        Ps[prow * 72 + 0 + l16]  = (bf16_t)p0;
        Ps[prow * 72 + 16 + l16] = (bf16_t)p1;
        Ps[prow * 72 + 32 + l16] = (bf16_t)p2;
        Ps[prow * 72 + 48 + l16] = (bf16_t)p3;
        lrow[mf][r] += (p0 + p1) + (p2 + p3);
      }
    }

    // O += P V
#pragma unroll
    for (int kf2 = 0; kf2 < 2; ++kf2) {
      bf16x8 pa[2], vb[8];
#pragma unroll
      for (int mf = 0; mf < 2; ++mf)
        pa[mf] = *(const bf16x8*)&Ps[(wv * 32 + mf * 16 + l16) * 72 +
                                     kf2 * 32 + q4 * 8];
#pragma unroll
      for (int nf = 0; nf < 8; ++nf)
        vb[nf] = *(const bf16x8*)&Vts[(nf * 16 + l16) * 64 +
                                      ((((kf2 << 2) | q4) ^ (l16 & 7)) << 3)];
#pragma unroll
      for (int mf = 0; mf < 2; ++mf)
#pragma unroll
        for (int nf = 0; nf < 8; ++nf)
          oacc[mf][nf] = __builtin_amdgcn_mfma_f32_16x16x32_bf16(
              pa[mf], vb[nf], oacc[mf][nf], 0, 0, 0);
    }
  }

  // reduce l across the 16-lane row group, then normalize + store
  const int b = bh >> 4, h = bh & 15;
#pragma unroll
  for (int mf = 0; mf < 2; ++mf) {
#pragma unroll
    for (int r = 0; r < 4; ++r) {
      float l = lrow[mf][r];
      l += __shfl_xor(l, 1);
      l += __shfl_xor(l, 2);
      l += __shfl_xor(l, 4);
      l += __shfl_xor(l, 8);
      float inv = 1.f / l;
      int t = q0 + wv * 32 + mf * 16 + q4 * 4 + r;
      size_t base = ((size_t)b * 2048 + t) * 2048 + h * 128;
#pragma unroll
      for (int nf = 0; nf < 8; ++nf)
        ob[base + nf * 16 + l16] = (bf16_t)(oacc[mf][nf][r] * inv);
    }
  }
}

// ------------------------- projection GEMM ---------------------------------
__global__ __launch_bounds__(256, 2) void k_proj(
    const bf16_t* __restrict__ O, const bf16_t* __restrict__ Wp,
    float* __restrict__ Y) {
  const int K = 2048;
  __shared__ alignas(16) bf16_t As[128 * 64];
  __shared__ alignas(16) bf16_t Bs[128 * 64];
  const int tid = threadIdx.x;
  const int lane = tid & 63, wv = tid >> 6;
  const int wm = wv >> 1, wn = wv & 1;
  const int q4 = lane >> 4, l16 = lane & 15;
  const int m0 = blockIdx.x * 128, n0 = blockIdx.y * 128;

  const bf16_t* Ab = O + (size_t)m0 * K;
  const bf16_t* Wb = Wp + (size_t)n0 * K;

  f32x4 zero4 = {0.f, 0.f, 0.f, 0.f};
  f32x4 acc[4][4];
#pragma unroll
  for (int i = 0; i < 4; ++i)
#pragma unroll
    for (int j = 0; j < 4; ++j) acc[i][j] = zero4;

  for (int k0 = 0; k0 < K; k0 += 64) {
    __syncthreads();
#pragma unroll
    for (int i = 0; i < 4; ++i) {
      int ci = i * 256 + tid;
      glds16(Ab + (size_t)(ci >> 3) * K + k0 + (((ci & 7) ^ ((ci >> 3) & 7)) << 3),
             &As[(i * 256 + wv * 64) * 8]);
    }
#pragma unroll
    for (int i = 0; i < 4; ++i) {
      int ci = i * 256 + tid;
      glds16(Wb + (size_t)(ci >> 3) * K + k0 + (((ci & 7) ^ ((ci >> 3) & 7)) << 3),
             &Bs[(i * 256 + wv * 64) * 8]);
    }
    __syncthreads();
#pragma unroll
    for (int kk = 0; kk < 2; ++kk) {
      bf16x8 afrag[4], bfrag[4];
#pragma unroll
      for (int mf = 0; mf < 4; ++mf)
        afrag[mf] = *(const bf16x8*)&As[(wm * 64 + mf * 16 + l16) * 64 +
                                        ((((kk << 2) | q4) ^ (l16 & 7)) << 3)];
#pragma unroll
      for (int nf = 0; nf < 4; ++nf)
        bfrag[nf] = *(const bf16x8*)&Bs[(wn * 64 + nf * 16 + l16) * 64 +
                                        ((((kk << 2) | q4) ^ (l16 & 7)) << 3)];
#pragma unroll
      for (int mf = 0; mf < 4; ++mf)
#pragma unroll
        for (int nf = 0; nf < 4; ++nf)
          acc[mf][nf] = __builtin_amdgcn_mfma_f32_16x16x32_bf16(
              afrag[mf], bfrag[nf], acc[mf][nf], 0, 0, 0);
    }
  }
#pragma unroll
  for (int mf = 0; mf < 4; ++mf)
#pragma unroll
    for (int nf = 0; nf < 4; ++nf)
#pragma unroll
      for (int r = 0; r < 4; ++r) {
        int m = m0 + wm * 64 + mf * 16 + q4 * 4 + r;
        int n = n0 + wn * 64 + nf * 16 + l16;
        Y[(size_t)m * 2048 + n] = acc[mf][nf][r];
      }
}

// ------------------------- launch ------------------------------------------
extern "C" void kernel_launch(void* const* d_in, const int* in_sizes, int n_in,
                              void* d_out, int out_size, void* d_ws, size_t ws_size,
                              hipStream_t stream) {
  const float* x = (const float*)d_in[0];
  const float* wqkv = (const float*)d_in[1];
  const float* wproj = (const float*)d_in[2];

  float* y = (float*)d_out;
  float* kout = y + SLICE_;
  float* vout = y + 2 * SLICE_;

  char* w = (char*)d_ws;
  bf16_t* xb = (bf16_t*)w;      w += SLICE_ * 2;
  bf16_t* wqkvb = (bf16_t*)w;   w += (size_t)12582912 * 2;
  bf16_t* wprojb = (bf16_t*)w;  w += (size_t)4194304 * 2;
  bf16_t* qb = (bf16_t*)w;      w += SLICE_ * 2;  // scaled+rope'd q, (B,H,T,hd)
  bf16_t* kb = (bf16_t*)w;      w += SLICE_ * 2;  // rope'd k, (B,H,T,hd)
  bf16_t* vtb = (bf16_t*)w;     w += SLICE_ * 2;  // v, (B,H,hd,T)
  bf16_t* ob = (bf16_t*)w;      w += SLICE_ * 2;  // attn out, (B,T,C)
  float2* tab = (float2*)w;     w += (size_t)131072 * 8;
  (void)ws_size; (void)in_sizes; (void)n_in; (void)out_size;

  // 6291456 cvt float4s + 131072 tab entries = 6422528 threads = 25088 blocks
  k_prep<<<25088, 256, 0, stream>>>((const float4*)x, (const float4*)wqkv,
                                    (const float4*)wproj, (bf16x4v*)xb,
                                    (bf16x4v*)wqkvb, (bf16x4v*)wprojb, tab);

  dim3 gq(32, 48);
  k_qkv<<<gq, 256, 0, stream>>>(xb, wqkvb, tab, qb, kb, vtb, kout, vout);
  k_attn<<<512, 256, 0, stream>>>(qb, kb, vtb, ob);
  dim3 gp(32, 16);
  k_proj<<<gp, 256, 0, stream>>>(ob, wprojb, y);
}

// Round 9
// 428.262 us; speedup vs baseline: 1.0016x; 1.0016x over previous
//
#include <hip/hip_runtime.h>
#include <math.h>

// ---------------------------------------------------------------------------
// SelfAttention R11: exact R7 structure (best, 389.4 µs) + two isolated safe
// deltas: (1) exp2-fold (log2e into q pre-scale; attn uses exp2f) — verified
// numerically safe in R8/R9; (2) Ps stride 80->72 (store 4-way->2-way
// conflict, read 2-way->free). Next-tile loads remain AFTER the visibility
// barrier (R10 regression root cause: __syncthreads drains vmcnt(0), so
// loads issued before the barrier stall it for full memory latency).
// k_qkv / k_proj / k_prep unchanged from R7 (+ scale constant in k_qkv).
// ---------------------------------------------------------------------------

typedef __bf16 bf16_t;
typedef __bf16 bf16x8 __attribute__((ext_vector_type(8)));
typedef __bf16 bf16x4v __attribute__((ext_vector_type(4)));
typedef float  f32x4  __attribute__((ext_vector_type(4)));

#define B_  2
#define T_  2048
#define C_  2048
#define SLICE_ ((size_t)B_ * T_ * C_)  // 8388608

__device__ __forceinline__ void glds16(const void* g, void* l) {
  __builtin_amdgcn_global_load_lds(
      (__attribute__((address_space(1))) void*)(void*)(const_cast<void*>(g)),
      (__attribute__((address_space(3))) void*)(l), 16, 0, 0);
}

// ------------------------- fused f32->bf16 packs + rope table --------------
__global__ __launch_bounds__(256) void k_prep(
    const float4* __restrict__ x, const float4* __restrict__ wqkv,
    const float4* __restrict__ wproj, bf16x4v* __restrict__ xb,
    bf16x4v* __restrict__ wqkvb, bf16x4v* __restrict__ wprojb,
    float2* __restrict__ tab) {
  int i = blockIdx.x * 256 + threadIdx.x;
  if (i < 2097152) {
    float4 v = x[i];
    bf16x4v o;
    o[0] = (bf16_t)v.x; o[1] = (bf16_t)v.y; o[2] = (bf16_t)v.z; o[3] = (bf16_t)v.w;
    xb[i] = o;
  } else if (i < 5242880) {
    int j = i - 2097152;
    float4 v = wqkv[j];
    bf16x4v o;
    o[0] = (bf16_t)v.x; o[1] = (bf16_t)v.y; o[2] = (bf16_t)v.z; o[3] = (bf16_t)v.w;
    wqkvb[j] = o;
  } else if (i < 6291456) {
    int j = i - 5242880;
    float4 v = wproj[j];
    bf16x4v o;
    o[0] = (bf16_t)v.x; o[1] = (bf16_t)v.y; o[2] = (bf16_t)v.z; o[3] = (bf16_t)v.w;
    wprojb[j] = o;
  } else {
    int j = i - 6291456;  // 0..131071
    int t = j >> 6, jj = j & 63;
    float thf = (float)pow(10000.0, -(double)(2 * jj) / 128.0);
    float angf = (float)t * thf;
    double a = (double)angf;
    tab[j] = make_float2((float)cos(a), (float)sin(a));
  }
}

// ------------------------- QKV GEMM + RoPE epilogue ------------------------
// C[m,n] = sum_k X[m,k] W[n,k]; M=4096, N=6144, K=2048. 128x128 tile, BK=64.
// LDS tiles xor-swizzled: LDS[row, c'] = global[row, c' ^ (row&7)] (16B chunks)
__global__ __launch_bounds__(256, 2) void k_qkv(
    const bf16_t* __restrict__ X, const bf16_t* __restrict__ W,
    const float2* __restrict__ tab,
    bf16_t* __restrict__ qb, bf16_t* __restrict__ kb, bf16_t* __restrict__ vtb,
    float* __restrict__ kout, float* __restrict__ vout) {
  const int K = 2048;
  __shared__ alignas(16) bf16_t smem[17408];  // As|Bs (16384) U epilogue 128x136
  bf16_t* As = smem;
  bf16_t* Bs = smem + 8192;
  const int tid = threadIdx.x;
  const int lane = tid & 63, wv = tid >> 6;
  const int wm = wv >> 1, wn = wv & 1;
  const int q4 = lane >> 4, l16 = lane & 15;
  const int m0 = blockIdx.x * 128, n0 = blockIdx.y * 128;

  const bf16_t* Ab = X + (size_t)m0 * K;
  const bf16_t* Wb = W + (size_t)n0 * K;

  f32x4 zero4 = {0.f, 0.f, 0.f, 0.f};
  f32x4 acc[4][4];
#pragma unroll
  for (int i = 0; i < 4; ++i)
#pragma unroll
    for (int j = 0; j < 4; ++j) acc[i][j] = zero4;

  for (int k0 = 0; k0 < K; k0 += 64) {
    __syncthreads();
#pragma unroll
    for (int i = 0; i < 4; ++i) {  // 128 rows x 8 chunks
      int ci = i * 256 + tid;
      glds16(Ab + (size_t)(ci >> 3) * K + k0 + (((ci & 7) ^ ((ci >> 3) & 7)) << 3),
             &As[(i * 256 + wv * 64) * 8]);
    }
#pragma unroll
    for (int i = 0; i < 4; ++i) {
      int ci = i * 256 + tid;
      glds16(Wb + (size_t)(ci >> 3) * K + k0 + (((ci & 7) ^ ((ci >> 3) & 7)) << 3),
             &Bs[(i * 256 + wv * 64) * 8]);
    }
    __syncthreads();
#pragma unroll
    for (int kk = 0; kk < 2; ++kk) {
      bf16x8 afrag[4], bfrag[4];
#pragma unroll
      for (int mf = 0; mf < 4; ++mf)
        afrag[mf] = *(const bf16x8*)&As[(wm * 64 + mf * 16 + l16) * 64 +
                                        ((((kk << 2) | q4) ^ (l16 & 7)) << 3)];
#pragma unroll
      for (int nf = 0; nf < 4; ++nf)
        bfrag[nf] = *(const bf16x8*)&Bs[(wn * 64 + nf * 16 + l16) * 64 +
                                        ((((kk << 2) | q4) ^ (l16 & 7)) << 3)];
#pragma unroll
      for (int mf = 0; mf < 4; ++mf)
#pragma unroll
        for (int nf = 0; nf < 4; ++nf)
          acc[mf][nf] = __builtin_amdgcn_mfma_f32_16x16x32_bf16(
              afrag[mf], bfrag[nf], acc[mf][nf], 0, 0, 0);
    }
  }

  __syncthreads();  // smem reuse for epilogue staging
  const int sec = n0 >> 11;  // 0=q, 1=k, 2=v (block-uniform)
  const int t0 = m0 & 2047, bb = m0 >> 11, h = (n0 & 2047) >> 7;

  if (sec < 2) {
#pragma unroll
    for (int mf = 0; mf < 4; ++mf)
#pragma unroll
      for (int nf = 0; nf < 4; ++nf)
#pragma unroll
        for (int r = 0; r < 4; ++r) {
          int ml = wm * 64 + mf * 16 + q4 * 4 + r;
          int d = wn * 64 + nf * 16 + l16;
          float val = acc[mf][nf][r];
          float partner = __shfl_xor(val, 1);
          float2 cs = tab[(t0 + ml) * 64 + (d >> 1)];
          float rv = (d & 1) ? (val * cs.x + partner * cs.y)
                             : (val * cs.x - partner * cs.y);
          // fold 1/sqrt(hd) * log2(e) into q (attn uses exp2)
          if (sec == 0) rv *= 0.08838834764831845f * 1.4426950408889634f;
          else kout[(size_t)(m0 + ml) * 2048 + h * 128 + d] = val;
          smem[ml * 136 + d] = (bf16_t)rv;
        }
    __syncthreads();
    bf16_t* dst = (sec == 0 ? qb : kb);
    size_t gbase = ((size_t)(bb * 16 + h) * 2048 + t0) * 128;
#pragma unroll
    for (int i = 0; i < 8; ++i) {
      int ci = i * 256 + tid, ml = ci >> 4, cc = (ci & 15) * 8;
      *(bf16x8*)(dst + gbase + (size_t)ml * 128 + cc) =
          *(const bf16x8*)&smem[ml * 136 + cc];
    }
  } else {
#pragma unroll
    for (int mf = 0; mf < 4; ++mf)
#pragma unroll
      for (int nf = 0; nf < 4; ++nf)
#pragma unroll
        for (int r = 0; r < 4; ++r) {
          int ml = wm * 64 + mf * 16 + q4 * 4 + r;
          int d = wn * 64 + nf * 16 + l16;
          float val = acc[mf][nf][r];
          vout[((size_t)(bb * 16 + h) * 2048 + t0 + ml) * 128 + d] = val;
          smem[d * 136 + ml] = (bf16_t)val;  // transpose in LDS
        }
    __syncthreads();
#pragma unroll
    for (int i = 0; i < 8; ++i) {
      int ci = i * 256 + tid, dr = ci >> 4, cc = (ci & 15) * 8;
      *(bf16x8*)(vtb + ((size_t)((bb * 16 + h) * 128 + dr)) * 2048 + t0 + cc) =
          *(const bf16x8*)&smem[dr * 136 + cc];
    }
  }
}

// ------------------------- flash attention ---------------------------------
// block = (b,h) x 128 queries, 4 waves x 32 queries. KT=64. Q in registers.
// No-max softmax in exp2 domain (q pre-scaled by log2e/sqrt(hd)).
// T14 async-STAGE: next-tile loads issued AFTER the visibility barrier
// (so they overlap the full compute phase; __syncthreads drains vmcnt).
// Ps stride 72: store 2-way conflict (free), read conflict-free.
__global__ __launch_bounds__(256, 2) void k_attn(
    const bf16_t* __restrict__ qb, const bf16_t* __restrict__ kb,
    const bf16_t* __restrict__ vtb, bf16_t* __restrict__ ob) {
  __shared__ alignas(16) bf16_t Ps[128 * 72];   // P tile, stride 72
  __shared__ alignas(16) bf16_t Ks[64 * 128];   // swizzled
  __shared__ alignas(16) bf16_t Vts[128 * 64];  // swizzled, [d][key]

  const int tid = threadIdx.x;
  const int lane = tid & 63, wv = tid >> 6;
  const int q4 = lane >> 4, l16 = lane & 15;
  const int bh = blockIdx.x >> 4;
  const int q0 = (blockIdx.x & 15) * 128;

  const bf16_t* Qg = qb + (size_t)bh * T_ * 128 + (size_t)q0 * 128;
  const bf16_t* Kg = kb + (size_t)bh * T_ * 128;
  const bf16_t* Vg = vtb + (size_t)bh * 128 * T_;

  // Q frags straight from global (one-time, pre-scaled by log2e/sqrt(hd))
  bf16x8 qa[2][4];
#pragma unroll
  for (int mf = 0; mf < 2; ++mf)
#pragma unroll
    for (int kf = 0; kf < 4; ++kf)
      qa[mf][kf] = *(const bf16x8*)(Qg + (size_t)(wv * 32 + mf * 16 + l16) * 128 +
                                    kf * 32 + q4 * 8);

  f32x4 zero4 = {0.f, 0.f, 0.f, 0.f};
  float lrow[2][4];
  f32x4 oacc[2][8];
#pragma unroll
  for (int mf = 0; mf < 2; ++mf) {
#pragma unroll
    for (int r = 0; r < 4; ++r) lrow[mf][r] = 0.f;
#pragma unroll
    for (int nf = 0; nf < 8; ++nf) oacc[mf][nf] = zero4;
  }

  // ---- issue staging loads for tile 0 (K: 64x128, V: 128x64, swizzled) ----
  bf16x8 kst[4], vst[4];
#pragma unroll
  for (int i = 0; i < 4; ++i) {
    int ci = i * 256 + tid;
    kst[i] = *(const bf16x8*)(Kg + (size_t)(ci >> 4) * 128 +
                              (((ci & 15) ^ ((ci >> 4) & 7)) << 3));
    vst[i] = *(const bf16x8*)(Vg + (size_t)(ci >> 3) * T_ +
                              (((ci & 7) ^ ((ci >> 3) & 7)) << 3));
  }

  for (int key0 = 0; key0 < T_; key0 += 64) {
    __syncthreads();  // previous compute done reading Ks/Vts
#pragma unroll
    for (int i = 0; i < 4; ++i) {  // write staged regs (waits vmcnt via dep)
      int ci = i * 256 + tid;
      *(bf16x8*)&Ks[ci * 8] = kst[i];
      *(bf16x8*)&Vts[ci * 8] = vst[i];
    }
    __syncthreads();  // writes visible

    if (key0 + 64 < T_) {  // issue NEXT tile's loads; hide under compute
      const bf16_t* Kg2 = Kg + (size_t)(key0 + 64) * 128;
      const bf16_t* Vg2 = Vg + key0 + 64;
#pragma unroll
      for (int i = 0; i < 4; ++i) {
        int ci = i * 256 + tid;
        kst[i] = *(const bf16x8*)(Kg2 + (size_t)(ci >> 4) * 128 +
                                  (((ci & 15) ^ ((ci >> 4) & 7)) << 3));
        vst[i] = *(const bf16x8*)(Vg2 + (size_t)(ci >> 3) * T_ +
                                  (((ci & 7) ^ ((ci >> 3) & 7)) << 3));
      }
    }

    // S = Q K^T (pre-scaled, log2 domain)
    f32x4 sacc[2][4];
#pragma unroll
    for (int mf = 0; mf < 2; ++mf)
#pragma unroll
      for (int nf = 0; nf < 4; ++nf) sacc[mf][nf] = zero4;
#pragma unroll
    for (int kf = 0; kf < 4; ++kf) {
      bf16x8 bfrag[4];
#pragma unroll
      for (int nf = 0; nf < 4; ++nf)
        bfrag[nf] = *(const bf16x8*)&Ks[(nf * 16 + l16) * 128 +
                                        ((((kf << 2) | q4) ^ (l16 & 7)) << 3)];
#pragma unroll
      for (int mf = 0; mf < 2; ++mf)
#pragma unroll
        for (int nf = 0; nf < 4; ++nf)
          sacc[mf][nf] = __builtin_amdgcn_mfma_f32_16x16x32_bf16(
              qa[mf][kf], bfrag[nf], sacc[mf][nf], 0, 0, 0);
    }

    // 2^s + P to LDS; per-lane partial row sums (reduced after key loop)
#pragma unroll
    for (int mf = 0; mf < 2; ++mf) {
#pragma unroll
      for (int r = 0; r < 4; ++r) {
        float p0 = exp2f(sacc[mf][0][r]);
        float p1 = exp2f(sacc[mf][1][r]);
        float p2 = exp2f(sacc[mf][2][r]);
        float p3 = exp2f(sacc[mf][3][r]);
        int prow = wv * 32 + mf * 16 + q4 * 4 + r;
        Ps[prow * 72 + 0 + l16]  = (bf16_t)p0;
        Ps[prow * 72 + 16 + l16] = (bf16_t)p1;
        Ps[prow * 72 + 32 + l16] = (bf16_t)p2;
        Ps[prow * 72 + 48 + l16] = (bf16_t)p3;
        lrow[mf][r] += (p0 + p1) + (p2 + p3);
      }
    }

    // O += P V
#pragma unroll
    for (int kf2 = 0; kf2 < 2; ++kf2) {
      bf16x8 pa[2], vb[8];
#pragma unroll
      for (int mf = 0; mf < 2; ++mf)
        pa[mf] = *(const bf16x8*)&Ps[(wv * 32 + mf * 16 + l16) * 72 +
                                     kf2 * 32 + q4 * 8];
#pragma unroll
      for (int nf = 0; nf < 8; ++nf)
        vb[nf] = *(const bf16x8*)&Vts[(nf * 16 + l16) * 64 +
                                      ((((kf2 << 2) | q4) ^ (l16 & 7)) << 3)];
#pragma unroll
      for (int mf = 0; mf < 2; ++mf)
#pragma unroll
        for (int nf = 0; nf < 8; ++nf)
          oacc[mf][nf] = __builtin_amdgcn_mfma_f32_16x16x32_bf16(
              pa[mf], vb[nf], oacc[mf][nf], 0, 0, 0);
    }
  }

  // reduce l across the 16-lane row group, then normalize + store
  const int b = bh >> 4, h = bh & 15;
#pragma unroll
  for (int mf = 0; mf < 2; ++mf) {
#pragma unroll
    for (int r = 0; r < 4; ++r) {
      float l = lrow[mf][r];
      l += __shfl_xor(l, 1);
      l += __shfl_xor(l, 2);
      l += __shfl_xor(l, 4);
      l += __shfl_xor(l, 8);
      float inv = 1.f / l;
      int t = q0 + wv * 32 + mf * 16 + q4 * 4 + r;
      size_t base = ((size_t)b * 2048 + t) * 2048 + h * 128;
#pragma unroll
      for (int nf = 0; nf < 8; ++nf)
        ob[base + nf * 16 + l16] = (bf16_t)(oacc[mf][nf][r] * inv);
    }
  }
}

// ------------------------- projection GEMM ---------------------------------
__global__ __launch_bounds__(256, 2) void k_proj(
    const bf16_t* __restrict__ O, const bf16_t* __restrict__ Wp,
    float* __restrict__ Y) {
  const int K = 2048;
  __shared__ alignas(16) bf16_t As[128 * 64];
  __shared__ alignas(16) bf16_t Bs[128 * 64];
  const int tid = threadIdx.x;
  const int lane = tid & 63, wv = tid >> 6;
  const int wm = wv >> 1, wn = wv & 1;
  const int q4 = lane >> 4, l16 = lane & 15;
  const int m0 = blockIdx.x * 128, n0 = blockIdx.y * 128;

  const bf16_t* Ab = O + (size_t)m0 * K;
  const bf16_t* Wb = Wp + (size_t)n0 * K;

  f32x4 zero4 = {0.f, 0.f, 0.f, 0.f};
  f32x4 acc[4][4];
#pragma unroll
  for (int i = 0; i < 4; ++i)
#pragma unroll
    for (int j = 0; j < 4; ++j) acc[i][j] = zero4;

  for (int k0 = 0; k0 < K; k0 += 64) {
    __syncthreads();
#pragma unroll
    for (int i = 0; i < 4; ++i) {
      int ci = i * 256 + tid;
      glds16(Ab + (size_t)(ci >> 3) * K + k0 + (((ci & 7) ^ ((ci >> 3) & 7)) << 3),
             &As[(i * 256 + wv * 64) * 8]);
    }
#pragma unroll
    for (int i = 0; i < 4; ++i) {
      int ci = i * 256 + tid;
      glds16(Wb + (size_t)(ci >> 3) * K + k0 + (((ci & 7) ^ ((ci >> 3) & 7)) << 3),
             &Bs[(i * 256 + wv * 64) * 8]);
    }
    __syncthreads();
#pragma unroll
    for (int kk = 0; kk < 2; ++kk) {
      bf16x8 afrag[4], bfrag[4];
#pragma unroll
      for (int mf = 0; mf < 4; ++mf)
        afrag[mf] = *(const bf16x8*)&As[(wm * 64 + mf * 16 + l16) * 64 +
                                        ((((kk << 2) | q4) ^ (l16 & 7)) << 3)];
#pragma unroll
      for (int nf = 0; nf < 4; ++nf)
        bfrag[nf] = *(const bf16x8*)&Bs[(wn * 64 + nf * 16 + l16) * 64 +
                                        ((((kk << 2) | q4) ^ (l16 & 7)) << 3)];
#pragma unroll
      for (int mf = 0; mf < 4; ++mf)
#pragma unroll
        for (int nf = 0; nf < 4; ++nf)
          acc[mf][nf] = __builtin_amdgcn_mfma_f32_16x16x32_bf16(
              afrag[mf], bfrag[nf], acc[mf][nf], 0, 0, 0);
    }
  }
#pragma unroll
  for (int mf = 0; mf < 4; ++mf)
#pragma unroll
    for (int nf = 0; nf < 4; ++nf)
#pragma unroll
      for (int r = 0; r < 4; ++r) {
        int m = m0 + wm * 64 + mf * 16 + q4 * 4 + r;
        int n = n0 + wn * 64 + nf * 16 + l16;
        Y[(size_t)m * 2048 + n] = acc[mf][nf][r];
      }
}

// ------------------------- launch ------------------------------------------
extern "C" void kernel_launch(void* const* d_in, const int* in_sizes, int n_in,
                              void* d_out, int out_size, void* d_ws, size_t ws_size,
                              hipStream_t stream) {
  const float* x = (const float*)d_in[0];
  const float* wqkv = (const float*)d_in[1];
  const float* wproj = (const float*)d_in[2];

  float* y = (float*)d_out;
  float* kout = y + SLICE_;
  float* vout = y + 2 * SLICE_;

  char* w = (char*)d_ws;
  bf16_t* xb = (bf16_t*)w;      w += SLICE_ * 2;
  bf16_t* wqkvb = (bf16_t*)w;   w += (size_t)12582912 * 2;
  bf16_t* wprojb = (bf16_t*)w;  w += (size_t)4194304 * 2;
  bf16_t* qb = (bf16_t*)w;      w += SLICE_ * 2;  // scaled+rope'd q, (B,H,T,hd)
  bf16_t* kb = (bf16_t*)w;      w += SLICE_ * 2;  // rope'd k, (B,H,T,hd)
  bf16_t* vtb = (bf16_t*)w;     w += SLICE_ * 2;  // v, (B,H,hd,T)
  bf16_t* ob = (bf16_t*)w;      w += SLICE_ * 2;  // attn out, (B,T,C)
  float2* tab = (float2*)w;     w += (size_t)131072 * 8;
  (void)ws_size; (void)in_sizes; (void)n_in; (void)out_size;

  // 6291456 cvt float4s + 131072 tab entries = 6422528 threads = 25088 blocks
  k_prep<<<25088, 256, 0, stream>>>((const float4*)x, (const float4*)wqkv,
                                    (const float4*)wproj, (bf16x4v*)xb,
                                    (bf16x4v*)wqkvb, (bf16x4v*)wprojb, tab);

  dim3 gq(32, 48);
  k_qkv<<<gq, 256, 0, stream>>>(xb, wqkvb, tab, qb, kb, vtb, kout, vout);
  k_attn<<<512, 256, 0, stream>>>(qb, kb, vtb, ob);
  dim3 gp(32, 16);
  k_proj<<<gp, 256, 0, stream>>>(ob, wprojb, y);
}

// Round 10
// 384.809 us; speedup vs baseline: 1.1147x; 1.1129x over previous
//
#include <hip/hip_runtime.h>
#include <math.h>

// ---------------------------------------------------------------------------
// SelfAttention R12: exact restore of R7 (session best, 389.4 µs).
// R8-R11 established: every attn delta from this config is flat or negative
// (stride-72 cost ~39 µs despite favorable bank arithmetic; packed-P,
// setprio, L2-grouping, 256-row tiles all <= 0). Locking in the best state:
//  * k_prep: merged cvt x3 + rope table (one launch).
//  * k_qkv: 128x128 m97-structure, RoPE epilogue, ~925 TF (42% MfmaUtil —
//    structural ceiling of the 2-barrier loop).
//  * k_attn: 4-wave flash, Q-in-regs, no-max softmax (__expf), T14
//    async-stage with next-tile loads AFTER the visibility barrier.
//  * k_proj: 128x128 GEMM.
// ---------------------------------------------------------------------------

typedef __bf16 bf16_t;
typedef __bf16 bf16x8 __attribute__((ext_vector_type(8)));
typedef __bf16 bf16x4v __attribute__((ext_vector_type(4)));
typedef float  f32x4  __attribute__((ext_vector_type(4)));

#define B_  2
#define T_  2048
#define C_  2048
#define SLICE_ ((size_t)B_ * T_ * C_)  // 8388608

__device__ __forceinline__ void glds16(const void* g, void* l) {
  __builtin_amdgcn_global_load_lds(
      (__attribute__((address_space(1))) void*)(void*)(const_cast<void*>(g)),
      (__attribute__((address_space(3))) void*)(l), 16, 0, 0);
}

// ------------------------- fused f32->bf16 packs + rope table --------------
__global__ __launch_bounds__(256) void k_prep(
    const float4* __restrict__ x, const float4* __restrict__ wqkv,
    const float4* __restrict__ wproj, bf16x4v* __restrict__ xb,
    bf16x4v* __restrict__ wqkvb, bf16x4v* __restrict__ wprojb,
    float2* __restrict__ tab) {
  int i = blockIdx.x * 256 + threadIdx.x;
  if (i < 2097152) {
    float4 v = x[i];
    bf16x4v o;
    o[0] = (bf16_t)v.x; o[1] = (bf16_t)v.y; o[2] = (bf16_t)v.z; o[3] = (bf16_t)v.w;
    xb[i] = o;
  } else if (i < 5242880) {
    int j = i - 2097152;
    float4 v = wqkv[j];
    bf16x4v o;
    o[0] = (bf16_t)v.x; o[1] = (bf16_t)v.y; o[2] = (bf16_t)v.z; o[3] = (bf16_t)v.w;
    wqkvb[j] = o;
  } else if (i < 6291456) {
    int j = i - 5242880;
    float4 v = wproj[j];
    bf16x4v o;
    o[0] = (bf16_t)v.x; o[1] = (bf16_t)v.y; o[2] = (bf16_t)v.z; o[3] = (bf16_t)v.w;
    wprojb[j] = o;
  } else {
    int j = i - 6291456;  // 0..131071
    int t = j >> 6, jj = j & 63;
    float thf = (float)pow(10000.0, -(double)(2 * jj) / 128.0);
    float angf = (float)t * thf;
    double a = (double)angf;
    tab[j] = make_float2((float)cos(a), (float)sin(a));
  }
}

// ------------------------- QKV GEMM + RoPE epilogue ------------------------
// C[m,n] = sum_k X[m,k] W[n,k]; M=4096, N=6144, K=2048. 128x128 tile, BK=64.
// LDS tiles xor-swizzled: LDS[row, c'] = global[row, c' ^ (row&7)] (16B chunks)
__global__ __launch_bounds__(256, 2) void k_qkv(
    const bf16_t* __restrict__ X, const bf16_t* __restrict__ W,
    const float2* __restrict__ tab,
    bf16_t* __restrict__ qb, bf16_t* __restrict__ kb, bf16_t* __restrict__ vtb,
    float* __restrict__ kout, float* __restrict__ vout) {
  const int K = 2048;
  __shared__ alignas(16) bf16_t smem[17408];  // As|Bs (16384) U epilogue 128x136
  bf16_t* As = smem;
  bf16_t* Bs = smem + 8192;
  const int tid = threadIdx.x;
  const int lane = tid & 63, wv = tid >> 6;
  const int wm = wv >> 1, wn = wv & 1;
  const int q4 = lane >> 4, l16 = lane & 15;
  const int m0 = blockIdx.x * 128, n0 = blockIdx.y * 128;

  const bf16_t* Ab = X + (size_t)m0 * K;
  const bf16_t* Wb = W + (size_t)n0 * K;

  f32x4 zero4 = {0.f, 0.f, 0.f, 0.f};
  f32x4 acc[4][4];
#pragma unroll
  for (int i = 0; i < 4; ++i)
#pragma unroll
    for (int j = 0; j < 4; ++j) acc[i][j] = zero4;

  for (int k0 = 0; k0 < K; k0 += 64) {
    __syncthreads();
#pragma unroll
    for (int i = 0; i < 4; ++i) {  // 128 rows x 8 chunks
      int ci = i * 256 + tid;
      glds16(Ab + (size_t)(ci >> 3) * K + k0 + (((ci & 7) ^ ((ci >> 3) & 7)) << 3),
             &As[(i * 256 + wv * 64) * 8]);
    }
#pragma unroll
    for (int i = 0; i < 4; ++i) {
      int ci = i * 256 + tid;
      glds16(Wb + (size_t)(ci >> 3) * K + k0 + (((ci & 7) ^ ((ci >> 3) & 7)) << 3),
             &Bs[(i * 256 + wv * 64) * 8]);
    }
    __syncthreads();
#pragma unroll
    for (int kk = 0; kk < 2; ++kk) {
      bf16x8 afrag[4], bfrag[4];
#pragma unroll
      for (int mf = 0; mf < 4; ++mf)
        afrag[mf] = *(const bf16x8*)&As[(wm * 64 + mf * 16 + l16) * 64 +
                                        ((((kk << 2) | q4) ^ (l16 & 7)) << 3)];
#pragma unroll
      for (int nf = 0; nf < 4; ++nf)
        bfrag[nf] = *(const bf16x8*)&Bs[(wn * 64 + nf * 16 + l16) * 64 +
                                        ((((kk << 2) | q4) ^ (l16 & 7)) << 3)];
#pragma unroll
      for (int mf = 0; mf < 4; ++mf)
#pragma unroll
        for (int nf = 0; nf < 4; ++nf)
          acc[mf][nf] = __builtin_amdgcn_mfma_f32_16x16x32_bf16(
              afrag[mf], bfrag[nf], acc[mf][nf], 0, 0, 0);
    }
  }

  __syncthreads();  // smem reuse for epilogue staging
  const int sec = n0 >> 11;  // 0=q, 1=k, 2=v (block-uniform)
  const int t0 = m0 & 2047, bb = m0 >> 11, h = (n0 & 2047) >> 7;

  if (sec < 2) {
#pragma unroll
    for (int mf = 0; mf < 4; ++mf)
#pragma unroll
      for (int nf = 0; nf < 4; ++nf)
#pragma unroll
        for (int r = 0; r < 4; ++r) {
          int ml = wm * 64 + mf * 16 + q4 * 4 + r;
          int d = wn * 64 + nf * 16 + l16;
          float val = acc[mf][nf][r];
          float partner = __shfl_xor(val, 1);
          float2 cs = tab[(t0 + ml) * 64 + (d >> 1)];
          float rv = (d & 1) ? (val * cs.x + partner * cs.y)
                             : (val * cs.x - partner * cs.y);
          if (sec == 0) rv *= 0.08838834764831845f;  // fold 1/sqrt(hd) into q
          else kout[(size_t)(m0 + ml) * 2048 + h * 128 + d] = val;
          smem[ml * 136 + d] = (bf16_t)rv;
        }
    __syncthreads();
    bf16_t* dst = (sec == 0 ? qb : kb);
    size_t gbase = ((size_t)(bb * 16 + h) * 2048 + t0) * 128;
#pragma unroll
    for (int i = 0; i < 8; ++i) {
      int ci = i * 256 + tid, ml = ci >> 4, cc = (ci & 15) * 8;
      *(bf16x8*)(dst + gbase + (size_t)ml * 128 + cc) =
          *(const bf16x8*)&smem[ml * 136 + cc];
    }
  } else {
#pragma unroll
    for (int mf = 0; mf < 4; ++mf)
#pragma unroll
      for (int nf = 0; nf < 4; ++nf)
#pragma unroll
        for (int r = 0; r < 4; ++r) {
          int ml = wm * 64 + mf * 16 + q4 * 4 + r;
          int d = wn * 64 + nf * 16 + l16;
          float val = acc[mf][nf][r];
          vout[((size_t)(bb * 16 + h) * 2048 + t0 + ml) * 128 + d] = val;
          smem[d * 136 + ml] = (bf16_t)val;  // transpose in LDS
        }
    __syncthreads();
#pragma unroll
    for (int i = 0; i < 8; ++i) {
      int ci = i * 256 + tid, dr = ci >> 4, cc = (ci & 15) * 8;
      *(bf16x8*)(vtb + ((size_t)((bb * 16 + h) * 128 + dr)) * 2048 + t0 + cc) =
          *(const bf16x8*)&smem[dr * 136 + cc];
    }
  }
}

// ------------------------- flash attention ---------------------------------
// block = (b,h) x 128 queries, 4 waves x 32 queries. KT=64. Q in registers.
// No-max softmax: O_unnorm += exp(s) V; l += sum exp(s); normalize at end.
// T14 async-STAGE: K/V reg-staged; loads for tile t+1 issue AFTER the
// visibility barrier so HBM latency hides under MFMA/softmax (issuing them
// before a __syncthreads stalls it: barrier drains vmcnt to 0).
__global__ __launch_bounds__(256, 2) void k_attn(
    const bf16_t* __restrict__ qb, const bf16_t* __restrict__ kb,
    const bf16_t* __restrict__ vtb, bf16_t* __restrict__ ob) {
  __shared__ alignas(16) bf16_t Ps[128 * 80];   // P tile, stride 80
  __shared__ alignas(16) bf16_t Ks[64 * 128];   // swizzled
  __shared__ alignas(16) bf16_t Vts[128 * 64];  // swizzled, [d][key]

  const int tid = threadIdx.x;
  const int lane = tid & 63, wv = tid >> 6;
  const int q4 = lane >> 4, l16 = lane & 15;
  const int bh = blockIdx.x >> 4;
  const int q0 = (blockIdx.x & 15) * 128;

  const bf16_t* Qg = qb + (size_t)bh * T_ * 128 + (size_t)q0 * 128;
  const bf16_t* Kg = kb + (size_t)bh * T_ * 128;
  const bf16_t* Vg = vtb + (size_t)bh * 128 * T_;

  // Q frags straight from global (one-time, pre-scaled by 1/sqrt(hd))
  bf16x8 qa[2][4];
#pragma unroll
  for (int mf = 0; mf < 2; ++mf)
#pragma unroll
    for (int kf = 0; kf < 4; ++kf)
      qa[mf][kf] = *(const bf16x8*)(Qg + (size_t)(wv * 32 + mf * 16 + l16) * 128 +
                                    kf * 32 + q4 * 8);

  f32x4 zero4 = {0.f, 0.f, 0.f, 0.f};
  float lrow[2][4];
  f32x4 oacc[2][8];
#pragma unroll
  for (int mf = 0; mf < 2; ++mf) {
#pragma unroll
    for (int r = 0; r < 4; ++r) lrow[mf][r] = 0.f;
#pragma unroll
    for (int nf = 0; nf < 8; ++nf) oacc[mf][nf] = zero4;
  }

  // ---- issue staging loads for tile 0 (K: 64x128, V: 128x64, swizzled) ----
  bf16x8 kst[4], vst[4];
#pragma unroll
  for (int i = 0; i < 4; ++i) {
    int ci = i * 256 + tid;
    kst[i] = *(const bf16x8*)(Kg + (size_t)(ci >> 4) * 128 +
                              (((ci & 15) ^ ((ci >> 4) & 7)) << 3));
    vst[i] = *(const bf16x8*)(Vg + (size_t)(ci >> 3) * T_ +
                              (((ci & 7) ^ ((ci >> 3) & 7)) << 3));
  }

  for (int key0 = 0; key0 < T_; key0 += 64) {
    __syncthreads();  // previous compute done reading Ks/Vts
#pragma unroll
    for (int i = 0; i < 4; ++i) {  // write staged regs (waits vmcnt via dep)
      int ci = i * 256 + tid;
      *(bf16x8*)&Ks[ci * 8] = kst[i];
      *(bf16x8*)&Vts[ci * 8] = vst[i];
    }
    __syncthreads();  // writes visible

    if (key0 + 64 < T_) {  // issue NEXT tile's loads; hide under compute
      const bf16_t* Kg2 = Kg + (size_t)(key0 + 64) * 128;
      const bf16_t* Vg2 = Vg + key0 + 64;
#pragma unroll
      for (int i = 0; i < 4; ++i) {
        int ci = i * 256 + tid;
        kst[i] = *(const bf16x8*)(Kg2 + (size_t)(ci >> 4) * 128 +
                                  (((ci & 15) ^ ((ci >> 4) & 7)) << 3));
        vst[i] = *(const bf16x8*)(Vg2 + (size_t)(ci >> 3) * T_ +
                                  (((ci & 7) ^ ((ci >> 3) & 7)) << 3));
      }
    }

    // S = Q K^T (pre-scaled)
    f32x4 sacc[2][4];
#pragma unroll
    for (int mf = 0; mf < 2; ++mf)
#pragma unroll
      for (int nf = 0; nf < 4; ++nf) sacc[mf][nf] = zero4;
#pragma unroll
    for (int kf = 0; kf < 4; ++kf) {
      bf16x8 bfrag[4];
#pragma unroll
      for (int nf = 0; nf < 4; ++nf)
        bfrag[nf] = *(const bf16x8*)&Ks[(nf * 16 + l16) * 128 +
                                        ((((kf << 2) | q4) ^ (l16 & 7)) << 3)];
#pragma unroll
      for (int mf = 0; mf < 2; ++mf)
#pragma unroll
        for (int nf = 0; nf < 4; ++nf)
          sacc[mf][nf] = __builtin_amdgcn_mfma_f32_16x16x32_bf16(
              qa[mf][kf], bfrag[nf], sacc[mf][nf], 0, 0, 0);
    }

    // exp + P to LDS; per-lane partial row sums (reduced after key loop)
#pragma unroll
    for (int mf = 0; mf < 2; ++mf) {
#pragma unroll
      for (int r = 0; r < 4; ++r) {
        float p0 = __expf(sacc[mf][0][r]);
        float p1 = __expf(sacc[mf][1][r]);
        float p2 = __expf(sacc[mf][2][r]);
        float p3 = __expf(sacc[mf][3][r]);
        int prow = wv * 32 + mf * 16 + q4 * 4 + r;
        Ps[prow * 80 + 0 + l16]  = (bf16_t)p0;
        Ps[prow * 80 + 16 + l16] = (bf16_t)p1;
        Ps[prow * 80 + 32 + l16] = (bf16_t)p2;
        Ps[prow * 80 + 48 + l16] = (bf16_t)p3;
        lrow[mf][r] += (p0 + p1) + (p2 + p3);
      }
    }

    // O += P V
#pragma unroll
    for (int kf2 = 0; kf2 < 2; ++kf2) {
      bf16x8 pa[2], vb[8];
#pragma unroll
      for (int mf = 0; mf < 2; ++mf)
        pa[mf] = *(const bf16x8*)&Ps[(wv * 32 + mf * 16 + l16) * 80 +
                                     kf2 * 32 + q4 * 8];
#pragma unroll
      for (int nf = 0; nf < 8; ++nf)
        vb[nf] = *(const bf16x8*)&Vts[(nf * 16 + l16) * 64 +
                                      ((((kf2 << 2) | q4) ^ (l16 & 7)) << 3)];
#pragma unroll
      for (int mf = 0; mf < 2; ++mf)
#pragma unroll
        for (int nf = 0; nf < 8; ++nf)
          oacc[mf][nf] = __builtin_amdgcn_mfma_f32_16x16x32_bf16(
              pa[mf], vb[nf], oacc[mf][nf], 0, 0, 0);
    }
  }

  // reduce l across the 16-lane row group, then normalize + store
  const int b = bh >> 4, h = bh & 15;
#pragma unroll
  for (int mf = 0; mf < 2; ++mf) {
#pragma unroll
    for (int r = 0; r < 4; ++r) {
      float l = lrow[mf][r];
      l += __shfl_xor(l, 1);
      l += __shfl_xor(l, 2);
      l += __shfl_xor(l, 4);
      l += __shfl_xor(l, 8);
      float inv = 1.f / l;
      int t = q0 + wv * 32 + mf * 16 + q4 * 4 + r;
      size_t base = ((size_t)b * 2048 + t) * 2048 + h * 128;
#pragma unroll
      for (int nf = 0; nf < 8; ++nf)
        ob[base + nf * 16 + l16] = (bf16_t)(oacc[mf][nf][r] * inv);
    }
  }
}

// ------------------------- projection GEMM ---------------------------------
__global__ __launch_bounds__(256, 2) void k_proj(
    const bf16_t* __restrict__ O, const bf16_t* __restrict__ Wp,
    float* __restrict__ Y) {
  const int K = 2048;
  __shared__ alignas(16) bf16_t As[128 * 64];
  __shared__ alignas(16) bf16_t Bs[128 * 64];
  const int tid = threadIdx.x;
  const int lane = tid & 63, wv = tid >> 6;
  const int wm = wv >> 1, wn = wv & 1;
  const int q4 = lane >> 4, l16 = lane & 15;
  const int m0 = blockIdx.x * 128, n0 = blockIdx.y * 128;

  const bf16_t* Ab = O + (size_t)m0 * K;
  const bf16_t* Wb = Wp + (size_t)n0 * K;

  f32x4 zero4 = {0.f, 0.f, 0.f, 0.f};
  f32x4 acc[4][4];
#pragma unroll
  for (int i = 0; i < 4; ++i)
#pragma unroll
    for (int j = 0; j < 4; ++j) acc[i][j] = zero4;

  for (int k0 = 0; k0 < K; k0 += 64) {
    __syncthreads();
#pragma unroll
    for (int i = 0; i < 4; ++i) {
      int ci = i * 256 + tid;
      glds16(Ab + (size_t)(ci >> 3) * K + k0 + (((ci & 7) ^ ((ci >> 3) & 7)) << 3),
             &As[(i * 256 + wv * 64) * 8]);
    }
#pragma unroll
    for (int i = 0; i < 4; ++i) {
      int ci = i * 256 + tid;
      glds16(Wb + (size_t)(ci >> 3) * K + k0 + (((ci & 7) ^ ((ci >> 3) & 7)) << 3),
             &Bs[(i * 256 + wv * 64) * 8]);
    }
    __syncthreads();
#pragma unroll
    for (int kk = 0; kk < 2; ++kk) {
      bf16x8 afrag[4], bfrag[4];
#pragma unroll
      for (int mf = 0; mf < 4; ++mf)
        afrag[mf] = *(const bf16x8*)&As[(wm * 64 + mf * 16 + l16) * 64 +
                                        ((((kk << 2) | q4) ^ (l16 & 7)) << 3)];
#pragma unroll
      for (int nf = 0; nf < 4; ++nf)
        bfrag[nf] = *(const bf16x8*)&Bs[(wn * 64 + nf * 16 + l16) * 64 +
                                        ((((kk << 2) | q4) ^ (l16 & 7)) << 3)];
#pragma unroll
      for (int mf = 0; mf < 4; ++mf)
#pragma unroll
        for (int nf = 0; nf < 4; ++nf)
          acc[mf][nf] = __builtin_amdgcn_mfma_f32_16x16x32_bf16(
              afrag[mf], bfrag[nf], acc[mf][nf], 0, 0, 0);
    }
  }
#pragma unroll
  for (int mf = 0; mf < 4; ++mf)
#pragma unroll
    for (int nf = 0; nf < 4; ++nf)
#pragma unroll
      for (int r = 0; r < 4; ++r) {
        int m = m0 + wm * 64 + mf * 16 + q4 * 4 + r;
        int n = n0 + wn * 64 + nf * 16 + l16;
        Y[(size_t)m * 2048 + n] = acc[mf][nf][r];
      }
}

// ------------------------- launch ------------------------------------------
extern "C" void kernel_launch(void* const* d_in, const int* in_sizes, int n_in,
                              void* d_out, int out_size, void* d_ws, size_t ws_size,
                              hipStream_t stream) {
  const float* x = (const float*)d_in[0];
  const float* wqkv = (const float*)d_in[1];
  const float* wproj = (const float*)d_in[2];

  float* y = (float*)d_out;
  float* kout = y + SLICE_;
  float* vout = y + 2 * SLICE_;

  char* w = (char*)d_ws;
  bf16_t* xb = (bf16_t*)w;      w += SLICE_ * 2;
  bf16_t* wqkvb = (bf16_t*)w;   w += (size_t)12582912 * 2;
  bf16_t* wprojb = (bf16_t*)w;  w += (size_t)4194304 * 2;
  bf16_t* qb = (bf16_t*)w;      w += SLICE_ * 2;  // scaled+rope'd q, (B,H,T,hd)
  bf16_t* kb = (bf16_t*)w;      w += SLICE_ * 2;  // rope'd k, (B,H,T,hd)
  bf16_t* vtb = (bf16_t*)w;     w += SLICE_ * 2;  // v, (B,H,hd,T)
  bf16_t* ob = (bf16_t*)w;      w += SLICE_ * 2;  // attn out, (B,T,C)
  float2* tab = (float2*)w;     w += (size_t)131072 * 8;
  (void)ws_size; (void)in_sizes; (void)n_in; (void)out_size;

  // 6291456 cvt float4s + 131072 tab entries = 6422528 threads = 25088 blocks
  k_prep<<<25088, 256, 0, stream>>>((const float4*)x, (const float4*)wqkv,
                                    (const float4*)wproj, (bf16x4v*)xb,
                                    (bf16x4v*)wqkvb, (bf16x4v*)wprojb, tab);

  dim3 gq(32, 48);
  k_qkv<<<gq, 256, 0, stream>>>(xb, wqkvb, tab, qb, kb, vtb, kout, vout);
  k_attn<<<512, 256, 0, stream>>>(qb, kb, vtb, ob);
  dim3 gp(32, 16);
  k_proj<<<gp, 256, 0, stream>>>(ob, wprojb, y);
}